// Round 4
// baseline (165.628 us; speedup 1.0000x reference)
//
#include <hip/hip_runtime.h>
#include <math.h>

#define BATCH 4
#define CH    256
#define NPIX  4096
#define DQK   32

typedef short          s16;
typedef unsigned int   uint_t;
typedef __attribute__((ext_vector_type(8))) short short8;   // 8 bf16 (4 VGPRs)
typedef __attribute__((ext_vector_type(4))) float floatx4;  // MFMA C/D 16x16
typedef __attribute__((ext_vector_type(16))) float floatx16; // MFMA C/D 32x32

__device__ __forceinline__ s16 f2bf(float f) {
  union { float f; uint_t u; } v; v.f = f;
  return (s16)((v.u + 0x8000u) >> 16);
}
__device__ __forceinline__ uint_t pk2(float a, float b) {
  union { float f; uint_t u; } x, y; x.f = a; y.f = b;
  return (((y.u + 0x8000u) >> 16) << 16) | ((x.u + 0x8000u) >> 16);
}

// ============ prepack: W (fp32, rows Q32|K32|V256) -> bf16 [320][256] ======
__global__ __launch_bounds__(256) void prepack(
    const float* __restrict__ Wq, const float* __restrict__ bq,
    const float* __restrict__ Wk, const float* __restrict__ bk,
    const float* __restrict__ Wv, const float* __restrict__ bv,
    s16* __restrict__ Wbf, float* __restrict__ Bsw)
{
  const int gid = blockIdx.x * 256 + threadIdx.x;   // grid 80
  const int e0  = gid * 4;
  const int row = e0 >> 8, col = e0 & 255;
  const float* src = (row < 32) ? Wq + (size_t)row * 256
                   : (row < 64) ? Wk + (size_t)(row - 32) * 256
                                : Wv + (size_t)(row - 64) * 256;
  float4 f = *(const float4*)(src + col);
  uint2 o; o.x = pk2(f.x, f.y); o.y = pk2(f.z, f.w);
  *(uint2*)(Wbf + e0) = o;
  if (gid < 320)
    Bsw[gid] = (gid < 32) ? bq[gid] : (gid < 64) ? bk[gid - 32] : bv[gid - 64];
}

// ============ proj: [Q;K;V] = W'·X, 32-px tiles, grid 512 (2 blocks/CU) ====
// Out: Q,K bf16 [b][n][32] ; V in MFMA-fragment-tiled layout:
//   Vt[((b*8+c)*256+s)*512 + lane*8 + j] = V[c*32+(lane&31)][s*16+8*(lane>>5)+j]
// so attn's A-frag load for (c, k16-block s) is ONE coalesced 1KB b128/wave.
__global__ __launch_bounds__(256, 2) void proj_mfma(
    const float* __restrict__ x, const s16* __restrict__ Wbf,
    const float* __restrict__ Bsw,
    s16* __restrict__ Qw, s16* __restrict__ Kw, s16* __restrict__ Vw)
{
  const int b  = blockIdx.x >> 7;
  const int n0 = (blockIdx.x & 127) << 5;
  const int t  = threadIdx.x;

  __shared__ s16 Xs[32][264];   // [n][k] bf16
  __shared__ s16 Os[256][40];   // V-epilogue staging [c][px], pad 40 (16B rows)

  // ---- stage X tile transposed (fp32 -> bf16) ----
  const float* xb = x + (size_t)b * CH * NPIX + n0;
  #pragma unroll
  for (int i = 0; i < 2; ++i) {
    int task = i * 256 + t;
    int ncg  = task & 7;
    int kcg  = task >> 3;
    const float* src = xb + (size_t)(kcg * 4) * NPIX + ncg * 4;
    float rows[4][4];
    *(float4*)&rows[0][0] = *(const float4*)(src);
    *(float4*)&rows[1][0] = *(const float4*)(src + NPIX);
    *(float4*)&rows[2][0] = *(const float4*)(src + 2 * NPIX);
    *(float4*)&rows[3][0] = *(const float4*)(src + 3 * NPIX);
    #pragma unroll
    for (int c = 0; c < 4; ++c) {
      uint2 pk;
      pk.x = pk2(rows[0][c], rows[1][c]);
      pk.y = pk2(rows[2][c], rows[3][c]);
      *(uint2*)&Xs[ncg * 4 + c][kcg * 4] = pk;
    }
  }
  __syncthreads();

  const int w    = t >> 6;
  const int l15  = t & 15;
  const int quad = (t & 63) >> 4;

  floatx4 acc[5][2];
  #pragma unroll
  for (int si = 0; si < 5; ++si)
    #pragma unroll
    for (int nt = 0; nt < 2; ++nt) acc[si][nt] = (floatx4){0.f, 0.f, 0.f, 0.f};

  // W fragments: register double-buffer to hide L2 latency
  short8 afc[5], afn[5];
  #pragma unroll
  for (int si = 0; si < 5; ++si) {
    const int s = w + si * 4;
    afc[si] = *(const short8*)(Wbf + (size_t)(s * 16 + l15) * 256 + quad * 8);
  }
  for (int kc = 0; kc < 8; ++kc) {
    const int k0  = kc * 32;
    const int kn0 = (kc < 7) ? k0 + 32 : 0;
    #pragma unroll
    for (int si = 0; si < 5; ++si) {
      const int s = w + si * 4;
      afn[si] = *(const short8*)(Wbf + (size_t)(s * 16 + l15) * 256 + kn0 + quad * 8);
    }
    short8 bf[2];
    #pragma unroll
    for (int nt = 0; nt < 2; ++nt)
      bf[nt] = *(const short8*)&Xs[l15 + 16 * nt][k0 + quad * 8];
    #pragma unroll
    for (int si = 0; si < 5; ++si)
      #pragma unroll
      for (int nt = 0; nt < 2; ++nt)
        acc[si][nt] = __builtin_amdgcn_mfma_f32_16x16x32_bf16(afc[si], bf[nt], acc[si][nt], 0, 0, 0);
    #pragma unroll
    for (int si = 0; si < 5; ++si) afc[si] = afn[si];
  }

  // ---- epilogue: Q/K direct; V staged in LDS then tiled-coalesced stores ----
  #pragma unroll
  for (int si = 0; si < 5; ++si) {
    const int s = w + si * 4;
    float4 bb = *(const float4*)(Bsw + 16 * s + quad * 4);
    #pragma unroll
    for (int nt = 0; nt < 2; ++nt) {
      const int px  = 16 * nt + l15;
      float v0 = acc[si][nt][0] + bb.x;
      float v1 = acc[si][nt][1] + bb.y;
      float v2 = acc[si][nt][2] + bb.z;
      float v3 = acc[si][nt][3] + bb.w;
      if (s < 4) {
        s16* dst = (s < 2) ? Qw : Kw;
        int d0 = (s & 1) * 16 + quad * 4;
        uint2 pq; pq.x = pk2(v0, v1); pq.y = pk2(v2, v3);
        *(uint2*)(dst + ((size_t)b * NPIX + n0 + px) * DQK + d0) = pq;
      } else {
        const int c0 = (s - 4) * 16 + quad * 4;
        Os[c0 + 0][px] = f2bf(v0);
        Os[c0 + 1][px] = f2bf(v1);
        Os[c0 + 2][px] = f2bf(v2);
        Os[c0 + 3][px] = f2bf(v3);
      }
    }
  }
  __syncthreads();
  // 1024 tasks = 16 frags (c 0..7 x sl 0..1) x 64 lanes, 16B coalesced stores
  #pragma unroll
  for (int rep = 0; rep < 4; ++rep) {
    const int task = rep * 256 + t;
    const int fid  = task >> 6;
    const int ln   = task & 63;
    const int c    = fid >> 1;
    const int sl   = fid & 1;
    const int row  = c * 32 + (ln & 31);
    const int col  = sl * 16 + (ln >> 5) * 8;
    *(uint4*)(Vw + (((size_t)b * 8 + c) * 256 + (n0 >> 4) + sl) * 512 + ln * 8) =
        *(const uint4*)&Os[row][col];
  }
}

// ============ attn: producer-consumer waves, grid 256 (1/CU), 16 waves =====
// block = (b = bi&3 [XCD-locked], qt = bi>>2), 64 queries, all 256 channels.
// S-waves  (w 0..7):  key strip sw=w (16 keys), ALL 64 q: 4 MFMA 16x16x32 +
//   16 exp + swizzled Pt write per tile. Runs one tile AHEAD of PV.
// PV-waves (w 8..15): ch-block c=w-8 (32 ch), FULL 128 k, ALL 64 q:
//   16 b128 Pt reads + 16 MFMA 32x32x16 per tile. V read-once (no kh split,
//   no Ored reduction). Pt double-buffer; 1 barrier/tile separates the roles,
//   so LDS pipe (PV) and VALU/exp (S) run CONCURRENTLY instead of lockstep.
__global__ __launch_bounds__(1024, 4) void attn_mfma(
    const s16* __restrict__ Qw, const s16* __restrict__ Kw,
    const s16* __restrict__ Vt, const float* __restrict__ x,
    float* __restrict__ out)
{
  const int bi = blockIdx.x;          // 256 blocks
  const int b  = bi & 3;              // XCD x -> batch x&3 (K/V/Q L2-resident)
  const int qt = bi >> 2;             // 0..63
  const int n0 = qt * 64;
  const int t  = threadIdx.x;
  const int w    = t >> 6;            // wave 0..15
  const int lane = t & 63;
  const int l15  = t & 15;
  const int quad = lane >> 4;
  const int l31  = t & 31;
  const int lh   = lane >> 5;
  const int l7   = t & 7;             // == row&7 for Pt write and read rows
  const bool is_s = (w < 8);
  const int sw   = w & 7;             // S: key strip | PV: ch-block c

  __shared__ s16  Pt[2][64][128];     // P^T, rows q (256B), swizzled 16B slots
  __shared__ float Lsum[64][8];

  const s16* kbase = Kw + (size_t)b * NPIX * DQK;
  const s16* vtb   = Vt + ((size_t)(b * 8 + sw) * 256) * 512 + lane * 8;

  // ---- S state ----
  short8 qb[4];
  short8 ka_c;
  float l_part[4] = {0.f, 0.f, 0.f, 0.f};
  // ---- PV state ----
  short8 va[8];
  floatx16 o[2];
  #pragma unroll
  for (int i = 0; i < 16; ++i) { o[0][i] = 0.f; o[1][i] = 0.f; }

  if (is_s) {
    const s16* qbase = Qw + ((size_t)b * NPIX + n0) * DQK;
    #pragma unroll
    for (int tq = 0; tq < 4; ++tq)
      qb[tq] = *(const short8*)(qbase + (size_t)(16 * tq + l15) * DQK + quad * 8);
    ka_c = *(const short8*)(kbase + (size_t)(16 * sw + l15) * DQK + quad * 8);
  } else {
    #pragma unroll
    for (int ks = 0; ks < 8; ++ks)
      va[ks] = *(const short8*)(vtb + (size_t)ks * 512);
  }

  const int wslot = (((2 * sw + (quad >> 1)) ^ l7) << 3) + (quad & 1) * 4;

  for (int kt = 0; kt < 32; ++kt) {
    if (is_s) {
      // ---- S^T strip for tile kt: keys 16sw+4quad+r, q = 16tq+l15 ----
      floatx4 sacc[4];
      #pragma unroll
      for (int tq = 0; tq < 4; ++tq)
        sacc[tq] = __builtin_amdgcn_mfma_f32_16x16x32_bf16(
                     ka_c, qb[tq], (floatx4){0.f, 0.f, 0.f, 0.f}, 0, 0, 0);

      const int mn0 = (kt < 31) ? (kt + 1) * 128 : 0;
      short8 ka_n = *(const short8*)(kbase +
                      (size_t)(mn0 + 16 * sw + l15) * DQK + quad * 8);

      #pragma unroll
      for (int tq = 0; tq < 4; ++tq) {
        float p0 = __expf(fminf(sacc[tq][0], 60.f));
        float p1 = __expf(fminf(sacc[tq][1], 60.f));
        float p2 = __expf(fminf(sacc[tq][2], 60.f));
        float p3 = __expf(fminf(sacc[tq][3], 60.f));
        l_part[tq] += (p0 + p1) + (p2 + p3);
        uint2 pk; pk.x = pk2(p0, p1); pk.y = pk2(p2, p3);
        *(uint2*)&Pt[kt & 1][16 * tq + l15][wslot] = pk;
      }
      ka_c = ka_n;
    } else if (kt > 0) {
      // ---- PV for tile kt-1: O[32ch][64q] += V·P^T ----
      const int buf = (kt - 1) & 1;
      #pragma unroll
      for (int ks = 0; ks < 8; ++ks) {
        const int rslot = ((2 * ks + lh) ^ l7) << 3;
        short8 pb0 = *(const short8*)&Pt[buf][l31     ][rslot];
        short8 pb1 = *(const short8*)&Pt[buf][32 + l31][rslot];
        o[0] = __builtin_amdgcn_mfma_f32_32x32x16_bf16(va[ks], pb0, o[0], 0, 0, 0);
        o[1] = __builtin_amdgcn_mfma_f32_32x32x16_bf16(va[ks], pb1, o[1], 0, 0, 0);
      }
      // refill V -> tile kt (consumed next iteration)
      const int sn = kt * 8;
      #pragma unroll
      for (int ks = 0; ks < 8; ++ks)
        va[ks] = *(const short8*)(vtb + (size_t)(sn + ks) * 512);
    }
    __syncthreads();   // publish Pt[kt&1]; PV done with Pt[(kt-1)&1]
  }

  // ---- tail: S reduces l; PV processes the last tile (buf = 31&1 = 1) ----
  if (is_s) {
    #pragma unroll
    for (int tq = 0; tq < 4; ++tq) {
      l_part[tq] += __shfl_xor(l_part[tq], 16);
      l_part[tq] += __shfl_xor(l_part[tq], 32);
    }
    if (quad == 0) {
      #pragma unroll
      for (int tq = 0; tq < 4; ++tq) Lsum[16 * tq + l15][sw] = l_part[tq];
    }
  } else {
    #pragma unroll
    for (int ks = 0; ks < 8; ++ks) {
      const int rslot = ((2 * ks + lh) ^ l7) << 3;
      short8 pb0 = *(const short8*)&Pt[1][l31     ][rslot];
      short8 pb1 = *(const short8*)&Pt[1][32 + l31][rslot];
      o[0] = __builtin_amdgcn_mfma_f32_32x32x16_bf16(va[ks], pb0, o[0], 0, 0, 0);
      o[1] = __builtin_amdgcn_mfma_f32_32x32x16_bf16(va[ks], pb1, o[1], 0, 0, 0);
    }
  }
  __syncthreads();

  // ---- epilogue (PV waves): normalize + residual. 32x32 C/D: col=q=l31,
  //      row = ch = c*32 + (r&3) + 8*(r>>2) + 4*lh ----
  if (!is_s) {
    const int q0 = l31, q1 = 32 + l31;
    float4 a0 = *(const float4*)&Lsum[q0][0];
    float4 a1 = *(const float4*)&Lsum[q0][4];
    float4 b0 = *(const float4*)&Lsum[q1][0];
    float4 b1 = *(const float4*)&Lsum[q1][4];
    float inv0 = 1.f / (((a0.x + a0.y) + (a0.z + a0.w)) +
                        ((a1.x + a1.y) + (a1.z + a1.w)));
    float inv1 = 1.f / (((b0.x + b0.y) + (b0.z + b0.w)) +
                        ((b1.x + b1.y) + (b1.z + b1.w)));
    #pragma unroll
    for (int r = 0; r < 16; ++r) {
      const int chrow = (r & 3) + 8 * (r >> 2) + 4 * lh;
      const int ch = sw * 32 + chrow;
      const size_t off0 = ((size_t)b * CH + ch) * NPIX + n0 + q0;
      const size_t off1 = ((size_t)b * CH + ch) * NPIX + n0 + q1;
      out[off0] = fmaf(o[0][r], inv0, x[off0]);
      out[off1] = fmaf(o[1][r], inv1, x[off1]);
    }
  }
}

extern "C" void kernel_launch(void* const* d_in, const int* in_sizes, int n_in,
                              void* d_out, int out_size, void* d_ws, size_t ws_size,
                              hipStream_t stream) {
  (void)in_sizes; (void)n_in; (void)out_size; (void)ws_size;
  const float* x  = (const float*)d_in[0];
  const float* Wq = (const float*)d_in[1];
  const float* bq = (const float*)d_in[2];
  const float* Wk = (const float*)d_in[3];
  const float* bk = (const float*)d_in[4];
  const float* Wv = (const float*)d_in[5];
  const float* bv = (const float*)d_in[6];
  float* out = (float*)d_out;

  // ws: Qw 1 MiB @0 | Kw @1 MiB | Vt @2 MiB (8 MiB, tiled) | Wbf @10 MiB |
  //     Bsw @10.25 MiB
  unsigned char* ws = (unsigned char*)d_ws;
  s16*   Qw  = (s16*)ws;
  s16*   Kw  = (s16*)(ws + (size_t)1 * 1024 * 1024);
  s16*   Vt  = (s16*)(ws + (size_t)2 * 1024 * 1024);
  s16*   Wbf = (s16*)(ws + (size_t)10 * 1024 * 1024);
  float* Bsw = (float*)(ws + (size_t)10 * 1024 * 1024 + 256 * 1024);

  hipLaunchKernelGGL(prepack, dim3(80), dim3(256), 0, stream,
                     Wq, bq, Wk, bk, Wv, bv, Wbf, Bsw);
  hipLaunchKernelGGL(proj_mfma, dim3(512), dim3(256), 0, stream,
                     x, Wbf, Bsw, Qw, Kw, Vt);
  hipLaunchKernelGGL(attn_mfma, dim3(256), dim3(1024), 0, stream,
                     Qw, Kw, Vt, x, out);
}

// Round 5
// 136.035 us; speedup vs baseline: 1.2175x; 1.2175x over previous
//
#include <hip/hip_runtime.h>
#include <math.h>

#define BATCH 4
#define CH    256
#define NPIX  4096
#define DQK   32

typedef short          s16;
typedef unsigned int   uint_t;
typedef __attribute__((ext_vector_type(8))) short short8;   // 8 bf16 (4 VGPRs)
typedef __attribute__((ext_vector_type(4))) float floatx4;  // MFMA C/D 16x16
typedef __attribute__((ext_vector_type(16))) float floatx16; // MFMA C/D 32x32

__device__ __forceinline__ s16 f2bf(float f) {
  union { float f; uint_t u; } v; v.f = f;
  return (s16)((v.u + 0x8000u) >> 16);
}
__device__ __forceinline__ uint_t pk2(float a, float b) {
  union { float f; uint_t u; } x, y; x.f = a; y.f = b;
  return (((y.u + 0x8000u) >> 16) << 16) | ((x.u + 0x8000u) >> 16);
}

// ============ prepack: W (fp32, rows Q32|K32|V256) -> bf16 [320][256] ======
__global__ __launch_bounds__(256) void prepack(
    const float* __restrict__ Wq, const float* __restrict__ bq,
    const float* __restrict__ Wk, const float* __restrict__ bk,
    const float* __restrict__ Wv, const float* __restrict__ bv,
    s16* __restrict__ Wbf, float* __restrict__ Bsw)
{
  const int gid = blockIdx.x * 256 + threadIdx.x;   // grid 80
  const int e0  = gid * 4;
  const int row = e0 >> 8, col = e0 & 255;
  const float* src = (row < 32) ? Wq + (size_t)row * 256
                   : (row < 64) ? Wk + (size_t)(row - 32) * 256
                                : Wv + (size_t)(row - 64) * 256;
  float4 f = *(const float4*)(src + col);
  uint2 o; o.x = pk2(f.x, f.y); o.y = pk2(f.z, f.w);
  *(uint2*)(Wbf + e0) = o;
  if (gid < 320)
    Bsw[gid] = (gid < 32) ? bq[gid] : (gid < 64) ? bk[gid - 32] : bv[gid - 64];
}

// ============ proj: [Q;K;V] = W'·X, 32-px tiles, grid 512 (2 blocks/CU) ====
// Out: Q,K bf16 [b][n][32] ; V in MFMA-fragment-tiled layout:
//   Vt[((b*8+c)*256+s)*512 + lane*8 + j] = V[c*32+(lane&31)][s*16+8*(lane>>5)+j]
// so attn's A-frag load for (c, k16-block s) is ONE coalesced 1KB b128/wave.
__global__ __launch_bounds__(256, 2) void proj_mfma(
    const float* __restrict__ x, const s16* __restrict__ Wbf,
    const float* __restrict__ Bsw,
    s16* __restrict__ Qw, s16* __restrict__ Kw, s16* __restrict__ Vw)
{
  const int b  = blockIdx.x >> 7;
  const int n0 = (blockIdx.x & 127) << 5;
  const int t  = threadIdx.x;

  __shared__ s16 Xs[32][264];   // [n][k] bf16
  __shared__ s16 Os[256][40];   // V-epilogue staging [c][px], pad 40 (16B rows)

  // ---- stage X tile transposed (fp32 -> bf16) ----
  const float* xb = x + (size_t)b * CH * NPIX + n0;
  #pragma unroll
  for (int i = 0; i < 2; ++i) {
    int task = i * 256 + t;
    int ncg  = task & 7;
    int kcg  = task >> 3;
    const float* src = xb + (size_t)(kcg * 4) * NPIX + ncg * 4;
    float rows[4][4];
    *(float4*)&rows[0][0] = *(const float4*)(src);
    *(float4*)&rows[1][0] = *(const float4*)(src + NPIX);
    *(float4*)&rows[2][0] = *(const float4*)(src + 2 * NPIX);
    *(float4*)&rows[3][0] = *(const float4*)(src + 3 * NPIX);
    #pragma unroll
    for (int c = 0; c < 4; ++c) {
      uint2 pk;
      pk.x = pk2(rows[0][c], rows[1][c]);
      pk.y = pk2(rows[2][c], rows[3][c]);
      *(uint2*)&Xs[ncg * 4 + c][kcg * 4] = pk;
    }
  }
  __syncthreads();

  const int w    = t >> 6;
  const int l15  = t & 15;
  const int quad = (t & 63) >> 4;

  floatx4 acc[5][2];
  #pragma unroll
  for (int si = 0; si < 5; ++si)
    #pragma unroll
    for (int nt = 0; nt < 2; ++nt) acc[si][nt] = (floatx4){0.f, 0.f, 0.f, 0.f};

  // W fragments: register double-buffer to hide L2 latency
  short8 afc[5], afn[5];
  #pragma unroll
  for (int si = 0; si < 5; ++si) {
    const int s = w + si * 4;
    afc[si] = *(const short8*)(Wbf + (size_t)(s * 16 + l15) * 256 + quad * 8);
  }
  for (int kc = 0; kc < 8; ++kc) {
    const int k0  = kc * 32;
    const int kn0 = (kc < 7) ? k0 + 32 : 0;
    #pragma unroll
    for (int si = 0; si < 5; ++si) {
      const int s = w + si * 4;
      afn[si] = *(const short8*)(Wbf + (size_t)(s * 16 + l15) * 256 + kn0 + quad * 8);
    }
    short8 bf[2];
    #pragma unroll
    for (int nt = 0; nt < 2; ++nt)
      bf[nt] = *(const short8*)&Xs[l15 + 16 * nt][k0 + quad * 8];
    #pragma unroll
    for (int si = 0; si < 5; ++si)
      #pragma unroll
      for (int nt = 0; nt < 2; ++nt)
        acc[si][nt] = __builtin_amdgcn_mfma_f32_16x16x32_bf16(afc[si], bf[nt], acc[si][nt], 0, 0, 0);
    #pragma unroll
    for (int si = 0; si < 5; ++si) afc[si] = afn[si];
  }

  // ---- epilogue: Q/K direct; V staged in LDS then tiled-coalesced stores ----
  #pragma unroll
  for (int si = 0; si < 5; ++si) {
    const int s = w + si * 4;
    float4 bb = *(const float4*)(Bsw + 16 * s + quad * 4);
    #pragma unroll
    for (int nt = 0; nt < 2; ++nt) {
      const int px  = 16 * nt + l15;
      float v0 = acc[si][nt][0] + bb.x;
      float v1 = acc[si][nt][1] + bb.y;
      float v2 = acc[si][nt][2] + bb.z;
      float v3 = acc[si][nt][3] + bb.w;
      if (s < 4) {
        s16* dst = (s < 2) ? Qw : Kw;
        int d0 = (s & 1) * 16 + quad * 4;
        uint2 pq; pq.x = pk2(v0, v1); pq.y = pk2(v2, v3);
        *(uint2*)(dst + ((size_t)b * NPIX + n0 + px) * DQK + d0) = pq;
      } else {
        const int c0 = (s - 4) * 16 + quad * 4;
        Os[c0 + 0][px] = f2bf(v0);
        Os[c0 + 1][px] = f2bf(v1);
        Os[c0 + 2][px] = f2bf(v2);
        Os[c0 + 3][px] = f2bf(v3);
      }
    }
  }
  __syncthreads();
  // 1024 tasks = 16 frags (c 0..7 x sl 0..1) x 64 lanes, 16B coalesced stores
  #pragma unroll
  for (int rep = 0; rep < 4; ++rep) {
    const int task = rep * 256 + t;
    const int fid  = task >> 6;
    const int ln   = task & 63;
    const int c    = fid >> 1;
    const int sl   = fid & 1;
    const int row  = c * 32 + (ln & 31);
    const int col  = sl * 16 + (ln >> 5) * 8;
    *(uint4*)(Vw + (((size_t)b * 8 + c) * 256 + (n0 >> 4) + sl) * 512 + ln * 8) =
        *(const uint4*)&Os[row][col];
  }
}

// ============ attn: 256 blocks (1/CU), 16 waves, K-split PV, pipelined =====
// block = (b = bi&3 [XCD-locked], qt = bi>>2), 64 queries, all 256 channels.
// Every wave does BOTH roles (shared state, no spills — r4 lesson):
//   S role:  key strip sw=w&7 (16 keys), q-half sq=w>>3.
//   PV role: ch-block c=w&7 (32 ch), key-half kh=w>>3 (V read-once).
// Iteration kt (software-pipelined, one barrier/tile):
//   1) pb[8] <- Pt[kt&1]          (DS reads issued early)
//   2) S for tile kt+1 -> Pt[kt&1 ^1]  (MFMA+exp+writes overlap DS latency)
//   3) PV MFMAs with pb (setprio) 4) V refill  5) barrier
// DS pipe stays fed through the whole window instead of bunching post-barrier.
__global__ __launch_bounds__(1024, 4) void attn_mfma(
    const s16* __restrict__ Qw, const s16* __restrict__ Kw,
    const s16* __restrict__ Vt, const float* __restrict__ x,
    float* __restrict__ out)
{
  const int bi = blockIdx.x;          // 256 blocks
  const int b  = bi & 3;              // XCD x -> batch x&3 (K/V/Q L2-resident)
  const int qt = bi >> 2;             // 0..63
  const int n0 = qt * 64;
  const int t  = threadIdx.x;
  const int w    = t >> 6;            // wave 0..15
  const int lane = t & 63;
  const int l15  = t & 15;
  const int quad = lane >> 4;
  const int l31  = t & 31;
  const int lh   = lane >> 5;
  const int l7   = t & 7;             // == row&7 for Pt write and read rows
  const int sw   = w & 7;             // S: key strip  == PV: ch-block c
  const int sq   = w >> 3;            // S: q half     == PV: key half kh
  const int kh   = sq;

  __shared__ s16  Pt[2][64][128];     // P^T, rows q (256B), swizzled 16B slots
  __shared__ float Lsum[64][8];
  __shared__ float Ored[8][32][64];   // kh=1 partial O for cross-kh reduction

  // Q B-frags persistent: B[d=8*quad+j][q = sq*32 + 16tq + l15]
  const s16* qbase = Qw + ((size_t)b * NPIX + n0 + sq * 32) * DQK;
  short8 qb[2];
  #pragma unroll
  for (int tq = 0; tq < 2; ++tq)
    qb[tq] = *(const short8*)(qbase + (size_t)(16 * tq + l15) * DQK + quad * 8);

  floatx16 o[2];                      // o[0]: q 0..31, o[1]: q 32..63
  #pragma unroll
  for (int i = 0; i < 16; ++i) { o[0][i] = 0.f; o[1][i] = 0.f; }
  float l_part[2] = {0.f, 0.f};

  const s16* kbase = Kw + (size_t)b * NPIX * DQK;
  const s16* vtb   = Vt + ((size_t)(b * 8 + sw) * 256) * 512 + lane * 8;

  // prefetch tile 0: K strip + V A-frags (coalesced 1KB tiled loads)
  short8 ka_c, ka_n, va[4];
  ka_c = *(const short8*)(kbase + (size_t)(16 * sw + l15) * DQK + quad * 8);
  #pragma unroll
  for (int ks = 0; ks < 4; ++ks)
    va[ks] = *(const short8*)(vtb + (size_t)(ks + 4 * kh) * 512);

  const int wslot = (((2 * sw + (quad >> 1)) ^ l7) << 3) + (quad & 1) * 4;

  // ---- prologue: S for tile 0 -> Pt[0] ----
  {
    floatx4 sacc[2];
    #pragma unroll
    for (int tq = 0; tq < 2; ++tq)
      sacc[tq] = __builtin_amdgcn_mfma_f32_16x16x32_bf16(
                   ka_c, qb[tq], (floatx4){0.f, 0.f, 0.f, 0.f}, 0, 0, 0);
    ka_n = *(const short8*)(kbase + (size_t)(128 + 16 * sw + l15) * DQK + quad * 8);
    #pragma unroll
    for (int tq = 0; tq < 2; ++tq) {
      float p0 = __expf(fminf(sacc[tq][0], 60.f));
      float p1 = __expf(fminf(sacc[tq][1], 60.f));
      float p2 = __expf(fminf(sacc[tq][2], 60.f));
      float p3 = __expf(fminf(sacc[tq][3], 60.f));
      l_part[tq] += (p0 + p1) + (p2 + p3);
      uint2 pk; pk.x = pk2(p0, p1); pk.y = pk2(p2, p3);
      *(uint2*)&Pt[0][sq * 32 + 16 * tq + l15][wslot] = pk;
    }
    ka_c = ka_n;
  }
  __syncthreads();

  for (int kt = 0; kt < 32; ++kt) {
    const int buf = kt & 1;

    // ---- 1) issue Pt reads for tile kt (latency hides under S below) ----
    short8 pb[4][2];
    #pragma unroll
    for (int ks = 0; ks < 4; ++ks) {
      const int rslot = ((2 * (ks + 4 * kh) + lh) ^ l7) << 3;
      pb[ks][0] = *(const short8*)&Pt[buf][l31     ][rslot];
      pb[ks][1] = *(const short8*)&Pt[buf][32 + l31][rslot];
    }

    // ---- 2) S for tile kt+1 -> Pt[buf^1] (disjoint buffer, no race) ----
    if (kt < 31) {
      floatx4 sacc[2];
      #pragma unroll
      for (int tq = 0; tq < 2; ++tq)
        sacc[tq] = __builtin_amdgcn_mfma_f32_16x16x32_bf16(
                     ka_c, qb[tq], (floatx4){0.f, 0.f, 0.f, 0.f}, 0, 0, 0);
      const int mn2 = (kt < 30) ? (kt + 2) * 128 : 0;
      ka_n = *(const short8*)(kbase + (size_t)(mn2 + 16 * sw + l15) * DQK + quad * 8);
      #pragma unroll
      for (int tq = 0; tq < 2; ++tq) {
        float p0 = __expf(fminf(sacc[tq][0], 60.f));
        float p1 = __expf(fminf(sacc[tq][1], 60.f));
        float p2 = __expf(fminf(sacc[tq][2], 60.f));
        float p3 = __expf(fminf(sacc[tq][3], 60.f));
        l_part[tq] += (p0 + p1) + (p2 + p3);
        uint2 pk; pk.x = pk2(p0, p1); pk.y = pk2(p2, p3);
        *(uint2*)&Pt[buf ^ 1][sq * 32 + 16 * tq + l15][wslot] = pk;
      }
      ka_c = ka_n;
    }

    // ---- 3) PV: O[32ch][64q] += V[32ch][64k_half]·P^T[64k_half][64q] ----
    __builtin_amdgcn_s_setprio(1);
    #pragma unroll
    for (int ks = 0; ks < 4; ++ks) {
      o[0] = __builtin_amdgcn_mfma_f32_32x32x16_bf16(va[ks], pb[ks][0], o[0], 0, 0, 0);
      o[1] = __builtin_amdgcn_mfma_f32_32x32x16_bf16(va[ks], pb[ks][1], o[1], 0, 0, 0);
    }
    __builtin_amdgcn_s_setprio(0);

    // ---- 4) V refill for tile kt+1 (wraps harmlessly at kt=31) ----
    const int sn = ((kt + 1) & 31) * 8;
    #pragma unroll
    for (int ks = 0; ks < 4; ++ks)
      va[ks] = *(const short8*)(vtb + (size_t)(sn + ks + 4 * kh) * 512);

    __syncthreads();   // publish Pt[buf^1]; all reads of Pt[buf] done
  }

  // ---- final l reduction: quads (shfl) then strips (LDS, once) ----
  #pragma unroll
  for (int tq = 0; tq < 2; ++tq) {
    l_part[tq] += __shfl_xor(l_part[tq], 16);
    l_part[tq] += __shfl_xor(l_part[tq], 32);
  }
  if (quad == 0) {
    #pragma unroll
    for (int tq = 0; tq < 2; ++tq) Lsum[sq * 32 + 16 * tq + l15][sw] = l_part[tq];
  }
  // kh=1 waves stage their partial O for reduction
  if (kh == 1) {
    #pragma unroll
    for (int r = 0; r < 16; ++r) {
      const int chrow = (r & 3) + 8 * (r >> 2) + 4 * lh;
      Ored[sw][chrow][l31]      = o[0][r];
      Ored[sw][chrow][32 + l31] = o[1][r];
    }
  }
  __syncthreads();

  // ---- epilogue (kh=0 waves): sum key-halves, normalize, residual ----
  if (kh == 0) {
    const int q0 = l31, q1 = 32 + l31;
    float4 a0 = *(const float4*)&Lsum[q0][0];
    float4 a1 = *(const float4*)&Lsum[q0][4];
    float4 b0 = *(const float4*)&Lsum[q1][0];
    float4 b1 = *(const float4*)&Lsum[q1][4];
    float inv0 = 1.f / (((a0.x + a0.y) + (a0.z + a0.w)) +
                        ((a1.x + a1.y) + (a1.z + a1.w)));
    float inv1 = 1.f / (((b0.x + b0.y) + (b0.z + b0.w)) +
                        ((b1.x + b1.y) + (b1.z + b1.w)));
    #pragma unroll
    for (int r = 0; r < 16; ++r) {
      const int chrow = (r & 3) + 8 * (r >> 2) + 4 * lh;
      const int ch = sw * 32 + chrow;
      const float s0 = o[0][r] + Ored[sw][chrow][l31];
      const float s1 = o[1][r] + Ored[sw][chrow][32 + l31];
      const size_t off0 = ((size_t)b * CH + ch) * NPIX + n0 + q0;
      const size_t off1 = ((size_t)b * CH + ch) * NPIX + n0 + q1;
      out[off0] = fmaf(s0, inv0, x[off0]);
      out[off1] = fmaf(s1, inv1, x[off1]);
    }
  }
}

extern "C" void kernel_launch(void* const* d_in, const int* in_sizes, int n_in,
                              void* d_out, int out_size, void* d_ws, size_t ws_size,
                              hipStream_t stream) {
  (void)in_sizes; (void)n_in; (void)out_size; (void)ws_size;
  const float* x  = (const float*)d_in[0];
  const float* Wq = (const float*)d_in[1];
  const float* bq = (const float*)d_in[2];
  const float* Wk = (const float*)d_in[3];
  const float* bk = (const float*)d_in[4];
  const float* Wv = (const float*)d_in[5];
  const float* bv = (const float*)d_in[6];
  float* out = (float*)d_out;

  // ws: Qw 1 MiB @0 | Kw @1 MiB | Vt @2 MiB (8 MiB, tiled) | Wbf @10 MiB |
  //     Bsw @10.25 MiB
  unsigned char* ws = (unsigned char*)d_ws;
  s16*   Qw  = (s16*)ws;
  s16*   Kw  = (s16*)(ws + (size_t)1 * 1024 * 1024);
  s16*   Vt  = (s16*)(ws + (size_t)2 * 1024 * 1024);
  s16*   Wbf = (s16*)(ws + (size_t)10 * 1024 * 1024);
  float* Bsw = (float*)(ws + (size_t)10 * 1024 * 1024 + 256 * 1024);

  hipLaunchKernelGGL(prepack, dim3(80), dim3(256), 0, stream,
                     Wq, bq, Wk, bk, Wv, bv, Wbf, Bsw);
  hipLaunchKernelGGL(proj_mfma, dim3(512), dim3(256), 0, stream,
                     x, Wbf, Bsw, Qw, Kw, Vt);
  hipLaunchKernelGGL(attn_mfma, dim3(256), dim3(1024), 0, stream,
                     Qw, Kw, Vt, x, out);
}